// Round 1
// baseline (304.033 us; speedup 1.0000x reference)
//
#include <hip/hip_runtime.h>
#include <cmath>

// ---------------------------------------------------------------------------
// Causal MHA. B=4, T=2048, C=1024, NH=16, HD=64.
//   0) cast x -> bf16; transpose-cast w_qkv, w_out -> bf16 [N,K]
//   1) qkv_bf16 = xb @ wqkvT^T      (m97-style bf16 MFMA GEMM, bf16 out)
//   1b) Vt[b,h][hd][T] = transpose of V
//   2) flash attention: 32x32x16 MFMA, S^T/O^T orientation, causal.
//      r1: T12 in-register P (cvt-pack + v_permlane32_swap_b32) -- no P LDS
//      round-trip; un-paired grid (64 x 16, snake qt map) for 4 blocks/CU.
//   3) out = ctxb @ woutT^T + b_out (bf16 MFMA GEMM, fp32 out)
// NOTE (r6 post-mortem, prev session): register prefetch + __launch_bounds__
// (256,4) caused scratch spill (WRITE_SIZE 16->107MB). Do NOT cap VGPRs or
// hold long-lived prefetch registers across the MFMA section in attention.
// ---------------------------------------------------------------------------

typedef __bf16 bf16x4 __attribute__((ext_vector_type(4)));
typedef __bf16 bf16x8 __attribute__((ext_vector_type(8)));
typedef float  f32x4  __attribute__((ext_vector_type(4)));
typedef float  f32x16 __attribute__((ext_vector_type(16)));

__device__ __forceinline__ void gload_lds16(const __bf16* g, __bf16* l) {
    __builtin_amdgcn_global_load_lds(
        (const __attribute__((address_space(1))) void*)g,
        (__attribute__((address_space(3))) void*)l,
        16, 0, 0);
}

// pack two f32 -> one u32 of 2 bf16 (compiler emits cvt + pack; m240 says do
// NOT hand-write v_cvt_pk_bf16_f32)
__device__ __forceinline__ unsigned packbf(float a, float b) {
    union { __bf16 h[2]; unsigned u; } t;
    t.h[0] = (__bf16)a; t.h[1] = (__bf16)b;
    return t.u;
}

// v_permlane32_swap_b32: after execution (derived from guide T12 verified
// usage): a = [a.lo | b.lo],  b = [a.hi | b.hi]   (lane i <-> lane i+32)
__device__ __forceinline__ void permswap(unsigned& a, unsigned& b) {
    asm volatile("v_permlane32_swap_b32 %0, %1" : "+v"(a), "+v"(b));
}

// ---- cast fp32 -> bf16, 4 elems/thread -------------------------------------
__global__ __launch_bounds__(256) void cast_bf16(const float* __restrict__ in,
                                                 __bf16* __restrict__ out, int n4) {
    int i = blockIdx.x * 256 + threadIdx.x;
    if (i >= n4) return;
    float4 f = *(const float4*)(in + (size_t)i * 4);
    bf16x4 o;
    o[0] = (__bf16)f.x; o[1] = (__bf16)f.y; o[2] = (__bf16)f.z; o[3] = (__bf16)f.w;
    *(bf16x4*)(out + (size_t)i * 4) = o;
}

// ---- transpose + cast: W[K,N] fp32 -> WT[N,K] bf16 -------------------------
__global__ __launch_bounds__(256) void transpose_cast(const float* __restrict__ W,
                                                      __bf16* __restrict__ WT,
                                                      int K, int N) {
    __shared__ float tile[32][33];
    const int n0 = blockIdx.x * 32, k0 = blockIdx.y * 32;
    const int tx = threadIdx.x & 31, ty = threadIdx.x >> 5;
    #pragma unroll
    for (int i = 0; i < 4; ++i)
        tile[ty + 8 * i][tx] = W[(size_t)(k0 + ty + 8 * i) * N + n0 + tx];
    __syncthreads();
    #pragma unroll
    for (int i = 0; i < 4; ++i)
        WT[(size_t)(n0 + ty + 8 * i) * K + k0 + tx] = (__bf16)tile[tx][ty + 8 * i];
}

// ---- V transpose: qkv V columns -> Vt[bh][hd=64][T=2048] -------------------
__global__ __launch_bounds__(256) void transpose_v(const __bf16* __restrict__ qkv,
                                                   __bf16* __restrict__ Vt) {
    constexpr int T = 2048, R3C = 3072;
    __shared__ __bf16 tile[64][72];
    const int bh = blockIdx.y;
    const int b  = bh >> 4, h = bh & 15;
    const int kt = blockIdx.x * 64;
    const int tid = threadIdx.x;
    #pragma unroll
    for (int i = 0; i < 2; ++i) {
        int idx = tid + 256 * i;
        int kr  = idx >> 3;
        int c8  = idx & 7;
        *(uint4*)&tile[kr][c8 * 8] =
            *(const uint4*)(qkv + (size_t)(b * T + kt + kr) * R3C + 2048 + h * 64 + c8 * 8);
    }
    __syncthreads();
    #pragma unroll
    for (int i = 0; i < 2; ++i) {
        int idx = tid + 256 * i;
        int d   = idx >> 3;
        int k8  = idx & 7;
        union { __bf16 v[8]; uint4 u; } t;
        #pragma unroll
        for (int j = 0; j < 8; ++j) t.v[j] = tile[k8 * 8 + j][d];
        *(uint4*)(Vt + ((size_t)bh * 64 + d) * T + kt + k8 * 8) = t.u;
    }
}

// ---------------------------------------------------------------------------
// m97-structure bf16 GEMM: C[M,N] = A[M,K] @ BT[N,K]^T (+bias).
// ---------------------------------------------------------------------------
template <typename OutT, bool BIAS>
__global__ __launch_bounds__(256) void gemm_bt(const __bf16* __restrict__ A,
                                               const __bf16* __restrict__ BT,
                                               OutT* __restrict__ Cc,
                                               const float* __restrict__ bias,
                                               int M, int N, int K) {
    __shared__ __bf16 As[128 * 32];
    __shared__ __bf16 Bs[128 * 32];

    const int tid  = threadIdx.x;
    const int lane = tid & 63;
    const int w    = tid >> 6;
    const int wr   = w >> 1, wc = w & 1;
    const int cc   = lane & 15, gg = lane >> 4;
    const int rowBase = blockIdx.y * 128;
    const int colBase = blockIdx.x * 128;

    f32x4 acc[4][4];
    #pragma unroll
    for (int i = 0; i < 4; ++i)
        #pragma unroll
        for (int j = 0; j < 4; ++j) acc[i][j] = f32x4{0.f, 0.f, 0.f, 0.f};

    for (int k0 = 0; k0 < K; k0 += 32) {
        __syncthreads();
        #pragma unroll
        for (int i = 0; i < 2; ++i) {
            int idx = tid + 256 * i;
            int r   = idx >> 2;
            int c4  = idx & 3;
            gload_lds16(A  + (size_t)(rowBase + r) * K + k0 + c4 * 8, &As[idx * 8]);
            gload_lds16(BT + (size_t)(colBase + r) * K + k0 + c4 * 8, &Bs[idx * 8]);
        }
        __syncthreads();

        bf16x8 af[4], bfr[4];
        #pragma unroll
        for (int i = 0; i < 4; ++i)
            af[i] = *(const bf16x8*)&As[(wr * 64 + i * 16 + cc) * 32 + gg * 8];
        #pragma unroll
        for (int j = 0; j < 4; ++j)
            bfr[j] = *(const bf16x8*)&Bs[(wc * 64 + j * 16 + cc) * 32 + gg * 8];
        #pragma unroll
        for (int i = 0; i < 4; ++i)
            #pragma unroll
            for (int j = 0; j < 4; ++j)
                acc[i][j] = __builtin_amdgcn_mfma_f32_16x16x32_bf16(af[i], bfr[j], acc[i][j], 0, 0, 0);
    }

    #pragma unroll
    for (int i = 0; i < 4; ++i)
        #pragma unroll
        for (int j = 0; j < 4; ++j) {
            const int col = colBase + wc * 64 + j * 16 + cc;
            #pragma unroll
            for (int r = 0; r < 4; ++r) {
                const int row = rowBase + wr * 64 + i * 16 + gg * 4 + r;
                float v = acc[i][j][r];
                if (BIAS) v += bias[col];
                Cc[(size_t)row * N + col] = (OutT)v;
            }
        }
}

// ---------------------------------------------------------------------------
// MFMA flash attention v5: 32x32x16 transposed orientation, causal,
// in-register P (T12: pack-to-bf16 + permlane32_swap), un-paired grid.
// Grid (bh=64, y=16); qt snake map so each 4-consecutive-y group sums to the
// average 68 tile-units (dispatch balance at 4 blocks/CU full residency).
// S^T = mfma(K_frag, Q_frag): col = q = lane&31,
//       row = key = (r&3) + 8*(r>>2) + 4*(lane>>5)   [guide m74/m101]
// P-fragment for O^T = mfma(V^T_frag, P_frag) needs lane(q) to hold
// P[key = 16*ks2 + half*8 + j][q]; pairs packed via packbf, cross-half words
// exchanged with one v_permlane32_swap_b32 per two words (lane L <-> L+32
// shares q). No Ps LDS buffer -> LDS 18432 B, no P lgkmcnt round-trip.
// Fixed-max softmax p = exp2(s*0.125*log2e - 16*log2e); L per-lane + one
// shfl_xor(32) at the end.
// ---------------------------------------------------------------------------
__global__ __launch_bounds__(256) void flash_attn_mfma(const __bf16* __restrict__ qkv,
                                                       const __bf16* __restrict__ Vt,
                                                       __bf16* __restrict__ ctx) {
    constexpr int T = 2048, C = 1024, NH = 16, HD = 64;
    constexpr int R3C = 3 * C;
    constexpr float K1 = 0.125f * 1.44269504088896f;   // scale * log2e
    constexpr float K2 = -16.0f * 1.44269504088896f;   // -M0 * log2e

    const int tid  = threadIdx.x;
    const int lane = tid & 63;
    const int w    = tid >> 6;
    const int q5   = lane & 31;                // q-col within wave tile
    const int half = lane >> 5;                // 0/1

    const int bh   = blockIdx.x;               // 0..63
    const int y    = blockIdx.y;               // 0..15
    const int qt   = (y & 1) ? (15 - (y >> 1)) : (y >> 1);   // snake balance
    const int b    = bh >> 4;
    const int h    = bh & 15;
    const int srow = qt * 128 + w * 32;
    const int ktmax = qt * 128 + 64;

    __shared__ __attribute__((aligned(16))) __bf16 Ks [64][72];   // [key][hd]
    __shared__ __attribute__((aligned(16))) __bf16 VsT[64][72];   // [hd][key]

    // Q as B-fragments: B[n=q5][k=ks*16+half*8+j]
    const __bf16* Qrow = qkv + (size_t)(b * T + srow + q5) * R3C + h * HD;
    bf16x8 Qb[4];
    #pragma unroll
    for (int ks = 0; ks < 4; ++ks)
        Qb[ks] = *(const bf16x8*)(Qrow + ks * 16 + half * 8);

    f32x16 O[2];
    #pragma unroll
    for (int mb = 0; mb < 2; ++mb)
        #pragma unroll
        for (int r = 0; r < 16; ++r) O[mb][r] = 0.f;
    float lsum = 0.f;

    const __bf16* Kb  = qkv + (size_t)(b * T) * R3C + C + h * HD;
    const __bf16* Vtb = Vt + (size_t)bh * 64 * T;

    for (int kt = 0; kt <= ktmax; kt += 64) {
        __syncthreads();
        // stage K tile: Ks[key][hd]
        #pragma unroll
        for (int i = 0; i < 2; ++i) {
            int idx = tid + 256 * i;
            int kr  = idx >> 3;
            int c8  = idx & 7;
            *(uint4*)&Ks[kr][c8 * 8] = *(const uint4*)(Kb + (size_t)(kt + kr) * R3C + c8 * 8);
        }
        // stage V^T tile: VsT[hd][key]
        #pragma unroll
        for (int i = 0; i < 2; ++i) {
            int idx = tid + 256 * i;
            int d   = idx >> 3;
            int k8  = idx & 7;
            *(uint4*)&VsT[d][k8 * 8] = *(const uint4*)(Vtb + (size_t)d * T + kt + k8 * 8);
        }
        __syncthreads();

        #pragma unroll
        for (int sub = 0; sub < 2; ++sub) {
            f32x16 S;
            #pragma unroll
            for (int r = 0; r < 16; ++r) S[r] = 0.f;
            #pragma unroll
            for (int ks = 0; ks < 4; ++ks) {
                bf16x8 kb = *(const bf16x8*)&Ks[sub * 32 + q5][ks * 16 + half * 8];
                S = __builtin_amdgcn_mfma_f32_32x32x16_bf16(kb, Qb[ks], S, 0, 0, 0);
            }
            if (kt + sub * 32 + 31 > srow) {
                #pragma unroll
                for (int r = 0; r < 16; ++r) {
                    int key = kt + sub * 32 + (r & 3) + 8 * (r >> 2) + 4 * half;
                    if (key > srow + q5) S[r] = -1e30f;
                }
            }
            // softmax (fixed max) -> f32 p, fully unrolled (registers only)
            float p[16];
            #pragma unroll
            for (int r = 0; r < 16; ++r) {
                p[r] = exp2f(fmaf(S[r], K1, K2));
                lsum += p[r];
            }
            // T12 in-register P->bf16 B-fragments.
            // half0 holds keys {0..3,8..11,16..19,24..27}(+sub*32), half1 the rest.
            // word w of B-frag slice s must hold keys 16*s + half*8 + {2w,2w+1}.
            unsigned w0 = packbf(p[0],  p[1]);    // h0:(0,1)   h1:(4,5)
            unsigned w1 = packbf(p[2],  p[3]);    // h0:(2,3)   h1:(6,7)
            unsigned w2 = packbf(p[4],  p[5]);    // h0:(8,9)   h1:(12,13)
            unsigned w3 = packbf(p[6],  p[7]);    // h0:(10,11) h1:(14,15)
            permswap(w0, w2);  // w0 -> slice0.word0, w2 -> slice0.word2
            permswap(w1, w3);  // w1 -> slice0.word1, w3 -> slice0.word3
            unsigned w4 = packbf(p[8],  p[9]);    // h0:(16,17) h1:(20,21)
            unsigned w5 = packbf(p[10], p[11]);   // h0:(18,19) h1:(22,23)
            unsigned w6 = packbf(p[12], p[13]);   // h0:(24,25) h1:(28,29)
            unsigned w7 = packbf(p[14], p[15]);   // h0:(26,27) h1:(30,31)
            permswap(w4, w6);  // w4 -> slice1.word0, w6 -> slice1.word2
            permswap(w5, w7);  // w5 -> slice1.word1, w7 -> slice1.word3
            union { unsigned u[4]; bf16x8 v; } pf0, pf1;
            pf0.u[0] = w0; pf0.u[1] = w1; pf0.u[2] = w2; pf0.u[3] = w3;
            pf1.u[0] = w4; pf1.u[1] = w5; pf1.u[2] = w6; pf1.u[3] = w7;

            // PV for this sub's two 16-deep k-slices
            const int ks20 = sub * 2;
            #pragma unroll
            for (int mb = 0; mb < 2; ++mb) {
                bf16x8 vb0 = *(const bf16x8*)&VsT[mb * 32 + q5][ks20 * 16 + half * 8];
                O[mb] = __builtin_amdgcn_mfma_f32_32x32x16_bf16(vb0, pf0.v, O[mb], 0, 0, 0);
                bf16x8 vb1 = *(const bf16x8*)&VsT[mb * 32 + q5][(ks20 + 1) * 16 + half * 8];
                O[mb] = __builtin_amdgcn_mfma_f32_32x32x16_bf16(vb1, pf1.v, O[mb], 0, 0, 0);
            }
        }
    }

    const float inv = 1.f / (lsum + __shfl_xor(lsum, 32));

    __bf16* crow = ctx + (size_t)(b * T + srow + q5) * C + h * HD;
    #pragma unroll
    for (int mb = 0; mb < 2; ++mb)
        #pragma unroll
        for (int a = 0; a < 4; ++a) {
            union { bf16x4 v; uint2 u; } pk;
            #pragma unroll
            for (int bq = 0; bq < 4; ++bq)
                pk.v[bq] = (__bf16)(O[mb][4 * a + bq] * inv);
            *(uint2*)(crow + mb * 32 + 8 * a + 4 * half) = pk.u;
        }
}

extern "C" void kernel_launch(void* const* d_in, const int* in_sizes, int n_in,
                              void* d_out, int out_size, void* d_ws, size_t ws_size,
                              hipStream_t stream) {
    constexpr int B = 4, T = 2048, C = 1024;
    constexpr int M = B * T;          // 8192

    const float* x     = (const float*)d_in[0];
    const float* w_qkv = (const float*)d_in[1];
    const float* w_out = (const float*)d_in[2];
    const float* b_out = (const float*)d_in[3];
    float* out = (float*)d_out;

    char* ws = (char*)d_ws;
    __bf16* xb     = (__bf16*)(ws);                      // 16 MB
    __bf16* wqkvT  = (__bf16*)(ws + (16ull << 20));      //  6 MB
    __bf16* woutT  = (__bf16*)(ws + (22ull << 20));      //  2 MB
    __bf16* qkvb   = (__bf16*)(ws + (24ull << 20));      // 48 MB
    __bf16* ctxb   = (__bf16*)(ws + (72ull << 20));      // 16 MB
    __bf16* Vt     = (__bf16*)(ws + (88ull << 20));      // 16 MB

    // 0) casts / transposes
    cast_bf16<<<(M * C / 4 + 255) / 256, 256, 0, stream>>>(x, xb, M * C / 4);
    transpose_cast<<<dim3(3 * C / 32, C / 32), 256, 0, stream>>>(w_qkv, wqkvT, C, 3 * C);
    transpose_cast<<<dim3(C / 32, C / 32), 256, 0, stream>>>(w_out, woutT, C, C);

    // 1) qkv = xb @ wqkvT^T  (bf16 out)
    gemm_bt<__bf16, false><<<dim3(3 * C / 128, M / 128), 256, 0, stream>>>(
        xb, wqkvT, qkvb, nullptr, M, 3 * C, C);

    // 1b) V transpose
    transpose_v<<<dim3(T / 64, B * 16), 256, 0, stream>>>(qkvb, Vt);

    // 2) MFMA flash attention -> ctxb (in-register P, un-paired causal grid)
    flash_attn_mfma<<<dim3(B * 16, 16), 256, 0, stream>>>(qkvb, Vt, ctxb);

    // 3) out = ctxb @ woutT^T + b_out (fp32 out)
    gemm_bt<float, true><<<dim3(C / 128, M / 128), 256, 0, stream>>>(
        ctxb, woutT, out, b_out, M, C, C);
}

// Round 2
// 299.661 us; speedup vs baseline: 1.0146x; 1.0146x over previous
//
#include <hip/hip_runtime.h>
#include <cmath>

// ---------------------------------------------------------------------------
// Causal MHA. B=4, T=2048, C=1024, NH=16, HD=64.
//   0) cast x -> bf16; transpose-cast w_qkv, w_out -> bf16 [N,K]
//   1) qkv_bf16 = xb @ wqkvT^T      (m97-style bf16 MFMA GEMM, bf16 out)
//   1b) Vt[b,h][hd][T] = transpose of V
//   2) flash attention v6: 32x32x16 MFMA, S^T/O^T orientation, causal,
//      in-register P (T12), PAIR of 64-row tiles per block with 2-way
//      INTRA-BLOCK SPLIT-K (fixed-max softmax -> partials just add).
//      Grid 64x16 uniform blocks (33 sub-tiles per wave, every wave).
//   3) out = ctxb @ woutT^T + b_out (bf16 MFMA GEMM, fp32 out)
// NOTE (prev session post-mortem): do NOT cap VGPRs via __launch_bounds__
// min-waves or hold long-lived prefetch regs across MFMA -> scratch spill.
// Q fragments are reloaded per iteration (fixed L2-hot addresses) to stay
// under the 128-VGPR occupancy cliff.
// ---------------------------------------------------------------------------

typedef __bf16 bf16x4 __attribute__((ext_vector_type(4)));
typedef __bf16 bf16x8 __attribute__((ext_vector_type(8)));
typedef float  f32x4  __attribute__((ext_vector_type(4)));
typedef float  f32x16 __attribute__((ext_vector_type(16)));

__device__ __forceinline__ void gload_lds16(const __bf16* g, __bf16* l) {
    __builtin_amdgcn_global_load_lds(
        (const __attribute__((address_space(1))) void*)g,
        (__attribute__((address_space(3))) void*)l,
        16, 0, 0);
}

// pack two f32 -> one u32 of 2 bf16 (compiler emits cvt_pk; m240: don't
// hand-write the asm)
__device__ __forceinline__ unsigned packbf(float a, float b) {
    union { __bf16 h[2]; unsigned u; } t;
    t.h[0] = (__bf16)a; t.h[1] = (__bf16)b;
    return t.u;
}

// v_permlane32_swap_b32: a = [a.lo | b.lo], b = [a.hi | b.hi] (lane i <-> i+32)
__device__ __forceinline__ void permswap(unsigned& a, unsigned& b) {
    asm volatile("v_permlane32_swap_b32 %0, %1" : "+v"(a), "+v"(b));
}

// ---- cast fp32 -> bf16, 4 elems/thread -------------------------------------
__global__ __launch_bounds__(256) void cast_bf16(const float* __restrict__ in,
                                                 __bf16* __restrict__ out, int n4) {
    int i = blockIdx.x * 256 + threadIdx.x;
    if (i >= n4) return;
    float4 f = *(const float4*)(in + (size_t)i * 4);
    bf16x4 o;
    o[0] = (__bf16)f.x; o[1] = (__bf16)f.y; o[2] = (__bf16)f.z; o[3] = (__bf16)f.w;
    *(bf16x4*)(out + (size_t)i * 4) = o;
}

// ---- transpose + cast: W[K,N] fp32 -> WT[N,K] bf16 -------------------------
__global__ __launch_bounds__(256) void transpose_cast(const float* __restrict__ W,
                                                      __bf16* __restrict__ WT,
                                                      int K, int N) {
    __shared__ float tile[32][33];
    const int n0 = blockIdx.x * 32, k0 = blockIdx.y * 32;
    const int tx = threadIdx.x & 31, ty = threadIdx.x >> 5;
    #pragma unroll
    for (int i = 0; i < 4; ++i)
        tile[ty + 8 * i][tx] = W[(size_t)(k0 + ty + 8 * i) * N + n0 + tx];
    __syncthreads();
    #pragma unroll
    for (int i = 0; i < 4; ++i)
        WT[(size_t)(n0 + ty + 8 * i) * K + k0 + tx] = (__bf16)tile[tx][ty + 8 * i];
}

// ---- V transpose: qkv V columns -> Vt[bh][hd=64][T=2048] -------------------
__global__ __launch_bounds__(256) void transpose_v(const __bf16* __restrict__ qkv,
                                                   __bf16* __restrict__ Vt) {
    constexpr int T = 2048, R3C = 3072;
    __shared__ __bf16 tile[64][72];
    const int bh = blockIdx.y;
    const int b  = bh >> 4, h = bh & 15;
    const int kt = blockIdx.x * 64;
    const int tid = threadIdx.x;
    #pragma unroll
    for (int i = 0; i < 2; ++i) {
        int idx = tid + 256 * i;
        int kr  = idx >> 3;
        int c8  = idx & 7;
        *(uint4*)&tile[kr][c8 * 8] =
            *(const uint4*)(qkv + (size_t)(b * T + kt + kr) * R3C + 2048 + h * 64 + c8 * 8);
    }
    __syncthreads();
    #pragma unroll
    for (int i = 0; i < 2; ++i) {
        int idx = tid + 256 * i;
        int d   = idx >> 3;
        int k8  = idx & 7;
        union { __bf16 v[8]; uint4 u; } t;
        #pragma unroll
        for (int j = 0; j < 8; ++j) t.v[j] = tile[k8 * 8 + j][d];
        *(uint4*)(Vt + ((size_t)bh * 64 + d) * T + kt + k8 * 8) = t.u;
    }
}

// ---------------------------------------------------------------------------
// m97-structure bf16 GEMM: C[M,N] = A[M,K] @ BT[N,K]^T (+bias).
// ---------------------------------------------------------------------------
template <typename OutT, bool BIAS>
__global__ __launch_bounds__(256) void gemm_bt(const __bf16* __restrict__ A,
                                               const __bf16* __restrict__ BT,
                                               OutT* __restrict__ Cc,
                                               const float* __restrict__ bias,
                                               int M, int N, int K) {
    __shared__ __bf16 As[128 * 32];
    __shared__ __bf16 Bs[128 * 32];

    const int tid  = threadIdx.x;
    const int lane = tid & 63;
    const int w    = tid >> 6;
    const int wr   = w >> 1, wc = w & 1;
    const int cc   = lane & 15, gg = lane >> 4;
    const int rowBase = blockIdx.y * 128;
    const int colBase = blockIdx.x * 128;

    f32x4 acc[4][4];
    #pragma unroll
    for (int i = 0; i < 4; ++i)
        #pragma unroll
        for (int j = 0; j < 4; ++j) acc[i][j] = f32x4{0.f, 0.f, 0.f, 0.f};

    for (int k0 = 0; k0 < K; k0 += 32) {
        __syncthreads();
        #pragma unroll
        for (int i = 0; i < 2; ++i) {
            int idx = tid + 256 * i;
            int r   = idx >> 2;
            int c4  = idx & 3;
            gload_lds16(A  + (size_t)(rowBase + r) * K + k0 + c4 * 8, &As[idx * 8]);
            gload_lds16(BT + (size_t)(colBase + r) * K + k0 + c4 * 8, &Bs[idx * 8]);
        }
        __syncthreads();

        bf16x8 af[4], bfr[4];
        #pragma unroll
        for (int i = 0; i < 4; ++i)
            af[i] = *(const bf16x8*)&As[(wr * 64 + i * 16 + cc) * 32 + gg * 8];
        #pragma unroll
        for (int j = 0; j < 4; ++j)
            bfr[j] = *(const bf16x8*)&Bs[(wc * 64 + j * 16 + cc) * 32 + gg * 8];
        #pragma unroll
        for (int i = 0; i < 4; ++i)
            #pragma unroll
            for (int j = 0; j < 4; ++j)
                acc[i][j] = __builtin_amdgcn_mfma_f32_16x16x32_bf16(af[i], bfr[j], acc[i][j], 0, 0, 0);
    }

    #pragma unroll
    for (int i = 0; i < 4; ++i)
        #pragma unroll
        for (int j = 0; j < 4; ++j) {
            const int col = colBase + wc * 64 + j * 16 + cc;
            #pragma unroll
            for (int r = 0; r < 4; ++r) {
                const int row = rowBase + wr * 64 + i * 16 + gg * 4 + r;
                float v = acc[i][j][r];
                if (BIAS) v += bias[col];
                Cc[(size_t)row * N + col] = (OutT)v;
            }
        }
}

// ---------------------------------------------------------------------------
// MFMA flash attention v6.
// Block = 4 waves = (strip in {0,1}) x (K-parity pr in {0,1}), covering a
// 64-row HEAVY tile A (ta = 31-p) and a 64-row LIGHT tile B (tb = p).
// Per iteration: stage 128 keys (K rows + V^T cols); wave (strip, pr)
// computes keys [kt + pr*64, +64) against its 32 q-rows of A then B.
// Fixed-max softmax (p = exp2(s*0.125*log2e - 16*log2e)) means split-K
// partials combine by plain addition: at the end, parity-1 waves dump
// (O_A, lsum_A) partials into the dead staging LDS, parity-0 waves add +
// normalize + store A; then roles swap for B.
// Per-wave work = (ta+1) + (tb+1) = 33 sub-tiles for EVERY wave -> uniform
// blocks, grid 64x16 = 4 blocks/CU all resident.
// S^T = mfma(K_frag, Q_frag): col = q = lane&31,
//       row = key = (r&3) + 8*(r>>2) + 4*(lane>>5)   [guide m74/m101]
// ---------------------------------------------------------------------------
__global__ __launch_bounds__(256) void flash_attn_mfma(const __bf16* __restrict__ qkv,
                                                       const __bf16* __restrict__ Vt,
                                                       __bf16* __restrict__ ctx) {
    constexpr int T = 2048, C = 1024, HD = 64;
    constexpr int R3C = 3 * C;
    constexpr float K1 = 0.125f * 1.44269504088896f;   // scale * log2e
    constexpr float K2 = -16.0f * 1.44269504088896f;   // -M0 * log2e

    const int tid  = threadIdx.x;
    const int lane = tid & 63;
    const int w    = tid >> 6;
    const int q5   = lane & 31;
    const int half = lane >> 5;
    const int strip = w & 1;                   // q-rows +0 / +32 within tile
    const int pr    = w >> 1;                  // K-parity: keys [kt+pr*64, +64)

    const int bh = blockIdx.x;                 // 0..63
    const int p  = blockIdx.y;                 // pair id 0..15
    const int b  = bh >> 4, h = bh & 15;
    const int ta = 31 - p, tb = p;             // 64-row tile indices
    const int srowA = ta * 64 + strip * 32;
    const int srowB = tb * 64 + strip * 32;
    const int nIter = (ta + 2) >> 1;           // ceil((ta+1)/2) 128-key steps

    // staging (35840 B) aliased with the split-K combine buffer (16640 B)
    __shared__ __attribute__((aligned(16))) char smem[35840];
    auto Ks   = (__bf16(*)[72])smem;             // [128][72]  key-major K
    auto VsT  = (__bf16(*)[136])(smem + 18432);  // [64][136]  hd-major V^T
    auto comb = (float(*)[32])smem;              // [128][32]  [strip*64+hd][q]
    float* combL = (float*)(smem + 16384);       // [2][32]    [strip][q]

    const __bf16* QrA = qkv + (size_t)(b * T + srowA + q5) * R3C + h * HD + half * 8;
    const __bf16* QrB = qkv + (size_t)(b * T + srowB + q5) * R3C + h * HD + half * 8;
    const __bf16* Kb  = qkv + (size_t)(b * T) * R3C + C + h * HD;
    const __bf16* Vtb = Vt + (size_t)bh * 64 * T;

    f32x16 OA[2], OB[2];
    #pragma unroll
    for (int mb = 0; mb < 2; ++mb)
        #pragma unroll
        for (int r = 0; r < 16; ++r) { OA[mb][r] = 0.f; OB[mb][r] = 0.f; }
    float lsA = 0.f, lsB = 0.f;

    for (int i = 0; i < nIter; ++i) {
        const int kt = i * 128;
        __syncthreads();
        // stage K tile: Ks[key 0..127][hd]
        #pragma unroll
        for (int j = 0; j < 4; ++j) {
            int idx = tid + 256 * j;
            int kr  = idx >> 3;
            int c8  = idx & 7;
            *(uint4*)&Ks[kr][c8 * 8] = *(const uint4*)(Kb + (size_t)(kt + kr) * R3C + c8 * 8);
        }
        // stage V^T tile: VsT[hd][key 0..127]
        #pragma unroll
        for (int j = 0; j < 4; ++j) {
            int idx = tid + 256 * j;
            int d   = idx >> 4;
            int k16 = idx & 15;
            *(uint4*)&VsT[d][k16 * 8] = *(const uint4*)(Vtb + (size_t)d * T + kt + k16 * 8);
        }
        __syncthreads();

        const int kw = kt + pr * 64;           // this wave's 64-key window

        auto tile = [&](const __bf16* Qr, int srow, f32x16* O, float& ls) {
            bf16x8 Qb[4];
            #pragma unroll
            for (int ks = 0; ks < 4; ++ks)
                Qb[ks] = *(const bf16x8*)(Qr + ks * 16);
            #pragma unroll
            for (int sub = 0; sub < 2; ++sub) {
                const int kb = kw + sub * 32;
                if (kb > srow + 31) continue;  // only reachable for sub==1
                f32x16 S;
                #pragma unroll
                for (int r = 0; r < 16; ++r) S[r] = 0.f;
                #pragma unroll
                for (int ks = 0; ks < 4; ++ks) {
                    bf16x8 kf = *(const bf16x8*)&Ks[pr * 64 + sub * 32 + q5][ks * 16 + half * 8];
                    S = __builtin_amdgcn_mfma_f32_32x32x16_bf16(kf, Qb[ks], S, 0, 0, 0);
                }
                if (kb + 31 > srow) {
                    #pragma unroll
                    for (int r = 0; r < 16; ++r) {
                        int key = kb + (r & 3) + 8 * (r >> 2) + 4 * half;
                        if (key > srow + q5) S[r] = -1e30f;
                    }
                }
                float pv[16];
                #pragma unroll
                for (int r = 0; r < 16; ++r) {
                    pv[r] = exp2f(fmaf(S[r], K1, K2));
                    ls += pv[r];
                }
                // T12 in-register P -> bf16 B-fragments (see r1 derivation)
                unsigned w0 = packbf(pv[0],  pv[1]);
                unsigned w1 = packbf(pv[2],  pv[3]);
                unsigned w2 = packbf(pv[4],  pv[5]);
                unsigned w3 = packbf(pv[6],  pv[7]);
                permswap(w0, w2);
                permswap(w1, w3);
                unsigned w4 = packbf(pv[8],  pv[9]);
                unsigned w5 = packbf(pv[10], pv[11]);
                unsigned w6 = packbf(pv[12], pv[13]);
                unsigned w7 = packbf(pv[14], pv[15]);
                permswap(w4, w6);
                permswap(w5, w7);
                union { unsigned u[4]; bf16x8 v; } pf0, pf1;
                pf0.u[0] = w0; pf0.u[1] = w1; pf0.u[2] = w2; pf0.u[3] = w3;
                pf1.u[0] = w4; pf1.u[1] = w5; pf1.u[2] = w6; pf1.u[3] = w7;
                const int vc = pr * 64 + sub * 32 + half * 8;
                #pragma unroll
                for (int mb = 0; mb < 2; ++mb) {
                    bf16x8 v0 = *(const bf16x8*)&VsT[mb * 32 + q5][vc];
                    O[mb] = __builtin_amdgcn_mfma_f32_32x32x16_bf16(v0, pf0.v, O[mb], 0, 0, 0);
                    bf16x8 v1 = *(const bf16x8*)&VsT[mb * 32 + q5][vc + 16];
                    O[mb] = __builtin_amdgcn_mfma_f32_32x32x16_bf16(v1, pf1.v, O[mb], 0, 0, 0);
                }
            }
        };

        if (kw <= srowA + 31) tile(QrA, srowA, OA, lsA);
        if (kw <= srowB + 31) tile(QrB, srowB, OB, lsB);
    }

    // ---- split-K combine (fixed max -> partials just add) ----
    const float lsAw = lsA + __shfl_xor(lsA, 32);
    const float lsBw = lsB + __shfl_xor(lsB, 32);

    __syncthreads();                            // staging LDS now dead
    if (pr == 1) {                              // pass A: parity-1 dumps
        #pragma unroll
        for (int mb = 0; mb < 2; ++mb)
            #pragma unroll
            for (int r = 0; r < 16; ++r)
                comb[strip * 64 + mb * 32 + (r & 3) + 8 * (r >> 2) + 4 * half][q5] = OA[mb][r];
        if (half == 0) combL[strip * 32 + q5] = lsAw;
    }
    __syncthreads();
    if (pr == 0) {                              // parity-0 combines + stores A
        const float inv = 1.f / (lsAw + combL[strip * 32 + q5]);
        __bf16* crow = ctx + (size_t)(b * T + srowA + q5) * C + h * HD;
        #pragma unroll
        for (int mb = 0; mb < 2; ++mb)
            #pragma unroll
            for (int a = 0; a < 4; ++a) {
                union { bf16x4 v; uint2 u; } pk;
                #pragma unroll
                for (int bq = 0; bq < 4; ++bq) {
                    float val = OA[mb][4 * a + bq]
                              + comb[strip * 64 + mb * 32 + 8 * a + 4 * half + bq][q5];
                    pk.v[bq] = (__bf16)(val * inv);
                }
                *(uint2*)(crow + mb * 32 + 8 * a + 4 * half) = pk.u;
            }
    }
    __syncthreads();
    if (pr == 0) {                              // pass B: parity-0 dumps
        #pragma unroll
        for (int mb = 0; mb < 2; ++mb)
            #pragma unroll
            for (int r = 0; r < 16; ++r)
                comb[strip * 64 + mb * 32 + (r & 3) + 8 * (r >> 2) + 4 * half][q5] = OB[mb][r];
        if (half == 0) combL[strip * 32 + q5] = lsBw;
    }
    __syncthreads();
    if (pr == 1) {                              // parity-1 combines + stores B
        const float inv = 1.f / (lsBw + combL[strip * 32 + q5]);
        __bf16* crow = ctx + (size_t)(b * T + srowB + q5) * C + h * HD;
        #pragma unroll
        for (int mb = 0; mb < 2; ++mb)
            #pragma unroll
            for (int a = 0; a < 4; ++a) {
                union { bf16x4 v; uint2 u; } pk;
                #pragma unroll
                for (int bq = 0; bq < 4; ++bq) {
                    float val = OB[mb][4 * a + bq]
                              + comb[strip * 64 + mb * 32 + 8 * a + 4 * half + bq][q5];
                    pk.v[bq] = (__bf16)(val * inv);
                }
                *(uint2*)(crow + mb * 32 + 8 * a + 4 * half) = pk.u;
            }
    }
}

extern "C" void kernel_launch(void* const* d_in, const int* in_sizes, int n_in,
                              void* d_out, int out_size, void* d_ws, size_t ws_size,
                              hipStream_t stream) {
    constexpr int B = 4, T = 2048, C = 1024;
    constexpr int M = B * T;          // 8192

    const float* x     = (const float*)d_in[0];
    const float* w_qkv = (const float*)d_in[1];
    const float* w_out = (const float*)d_in[2];
    const float* b_out = (const float*)d_in[3];
    float* out = (float*)d_out;

    char* ws = (char*)d_ws;
    __bf16* xb     = (__bf16*)(ws);                      // 16 MB
    __bf16* wqkvT  = (__bf16*)(ws + (16ull << 20));      //  6 MB
    __bf16* woutT  = (__bf16*)(ws + (22ull << 20));      //  2 MB
    __bf16* qkvb   = (__bf16*)(ws + (24ull << 20));      // 48 MB
    __bf16* ctxb   = (__bf16*)(ws + (72ull << 20));      // 16 MB
    __bf16* Vt     = (__bf16*)(ws + (88ull << 20));      // 16 MB

    // 0) casts / transposes
    cast_bf16<<<(M * C / 4 + 255) / 256, 256, 0, stream>>>(x, xb, M * C / 4);
    transpose_cast<<<dim3(3 * C / 32, C / 32), 256, 0, stream>>>(w_qkv, wqkvT, C, 3 * C);
    transpose_cast<<<dim3(C / 32, C / 32), 256, 0, stream>>>(w_out, woutT, C, C);

    // 1) qkv = xb @ wqkvT^T  (bf16 out)
    gemm_bt<__bf16, false><<<dim3(3 * C / 128, M / 128), 256, 0, stream>>>(
        xb, wqkvT, qkvb, nullptr, M, 3 * C, C);

    // 1b) V transpose
    transpose_v<<<dim3(T / 64, B * 16), 256, 0, stream>>>(qkvb, Vt);

    // 2) MFMA flash attention -> ctxb (pair + intra-block split-K, uniform)
    flash_attn_mfma<<<dim3(B * 16, 16), 256, 0, stream>>>(qkvb, Vt, ctxb);

    // 3) out = ctxb @ woutT^T + b_out (fp32 out)
    gemm_bt<float, true><<<dim3(C / 128, M / 128), 256, 0, stream>>>(
        ctxb, woutT, out, b_out, M, C, C);
}

// Round 3
// 280.766 us; speedup vs baseline: 1.0829x; 1.0673x over previous
//
#include <hip/hip_runtime.h>
#include <cmath>

// ---------------------------------------------------------------------------
// Causal MHA. B=4, T=2048, C=1024, NH=16, HD=64.
//   0) cast x -> bf16; transpose-cast w_qkv, w_out -> bf16 [N,K]
//   1) qkv = xb @ wqkvT^T  via gemm256: 256x256 tile, BK=64, 8 waves,
//      4-phase pipelined schedule (T2 swizzle + T3/T4 counted vmcnt + T5
//      setprio), raw s_barrier, global_load_lds w/ pre-swizzled source.
//   1b) Vt[b,h][hd][T] = transpose of V
//   2) flash attention v7 = r0 pair-fused balanced grid + T12 in-register P.
//   3) out = ctxb @ woutT^T + b_out (m97 128^2 GEMM, fp32 out)
// ---------------------------------------------------------------------------

typedef __bf16 bf16x4 __attribute__((ext_vector_type(4)));
typedef __bf16 bf16x8 __attribute__((ext_vector_type(8)));
typedef float  f32x4  __attribute__((ext_vector_type(4)));
typedef float  f32x16 __attribute__((ext_vector_type(16)));

__device__ __forceinline__ void gload_lds16(const __bf16* g, __bf16* l) {
    __builtin_amdgcn_global_load_lds(
        (const __attribute__((address_space(1))) void*)g,
        (__attribute__((address_space(3))) void*)l,
        16, 0, 0);
}

__device__ __forceinline__ unsigned packbf(float a, float b) {
    union { __bf16 h[2]; unsigned u; } t;
    t.h[0] = (__bf16)a; t.h[1] = (__bf16)b;
    return t.u;
}

// v_permlane32_swap_b32: a = [a.lo | b.lo], b = [a.hi | b.hi] (lane i <-> i+32)
__device__ __forceinline__ void permswap(unsigned& a, unsigned& b) {
    asm volatile("v_permlane32_swap_b32 %0, %1" : "+v"(a), "+v"(b));
}

#define BAR()  __builtin_amdgcn_s_barrier()
#define VM2()  { asm volatile("s_waitcnt vmcnt(2)" ::: "memory"); \
                 __builtin_amdgcn_sched_barrier(0); }

// ---- cast fp32 -> bf16, 4 elems/thread -------------------------------------
__global__ __launch_bounds__(256) void cast_bf16(const float* __restrict__ in,
                                                 __bf16* __restrict__ out, int n4) {
    int i = blockIdx.x * 256 + threadIdx.x;
    if (i >= n4) return;
    float4 f = *(const float4*)(in + (size_t)i * 4);
    bf16x4 o;
    o[0] = (__bf16)f.x; o[1] = (__bf16)f.y; o[2] = (__bf16)f.z; o[3] = (__bf16)f.w;
    *(bf16x4*)(out + (size_t)i * 4) = o;
}

// ---- transpose + cast: W[K,N] fp32 -> WT[N,K] bf16 -------------------------
__global__ __launch_bounds__(256) void transpose_cast(const float* __restrict__ W,
                                                      __bf16* __restrict__ WT,
                                                      int K, int N) {
    __shared__ float tile[32][33];
    const int n0 = blockIdx.x * 32, k0 = blockIdx.y * 32;
    const int tx = threadIdx.x & 31, ty = threadIdx.x >> 5;
    #pragma unroll
    for (int i = 0; i < 4; ++i)
        tile[ty + 8 * i][tx] = W[(size_t)(k0 + ty + 8 * i) * N + n0 + tx];
    __syncthreads();
    #pragma unroll
    for (int i = 0; i < 4; ++i)
        WT[(size_t)(n0 + ty + 8 * i) * K + k0 + tx] = (__bf16)tile[tx][ty + 8 * i];
}

// ---- V transpose: qkv V columns -> Vt[bh][hd=64][T=2048] -------------------
__global__ __launch_bounds__(256) void transpose_v(const __bf16* __restrict__ qkv,
                                                   __bf16* __restrict__ Vt) {
    constexpr int T = 2048, R3C = 3072;
    __shared__ __bf16 tile[64][72];
    const int bh = blockIdx.y;
    const int b  = bh >> 4, h = bh & 15;
    const int kt = blockIdx.x * 64;
    const int tid = threadIdx.x;
    #pragma unroll
    for (int i = 0; i < 2; ++i) {
        int idx = tid + 256 * i;
        int kr  = idx >> 3;
        int c8  = idx & 7;
        *(uint4*)&tile[kr][c8 * 8] =
            *(const uint4*)(qkv + (size_t)(b * T + kt + kr) * R3C + 2048 + h * 64 + c8 * 8);
    }
    __syncthreads();
    #pragma unroll
    for (int i = 0; i < 2; ++i) {
        int idx = tid + 256 * i;
        int d   = idx >> 3;
        int k8  = idx & 7;
        union { __bf16 v[8]; uint4 u; } t;
        #pragma unroll
        for (int j = 0; j < 8; ++j) t.v[j] = tile[k8 * 8 + j][d];
        *(uint4*)(Vt + ((size_t)bh * 64 + d) * T + kt + k8 * 8) = t.u;
    }
}

// ---------------------------------------------------------------------------
// gemm256: C[M,N] = A[M,K] @ BT[N,K]^T, bf16 out. 256x256 tile, BK=64,
// 512 threads = 8 waves (2M x 4N), wave tile 128x64, 16x16x32 MFMA.
// LDS: 2 buffers x (A 256x64 + B 256x64) bf16 = 128 KiB, linear layout for
// global_load_lds; T2 XOR swizzle (colbyte ^= (row&7)<<4) applied by
// pre-swizzling the GLOBAL source (per-lane) and the ds_read address.
// Schedule per K-tile t (4 phases), buffers by t&1:
//   ph1: ds_read A_m0(8) + all B(8); stage B_n0(t+1); BAR; MFMA m0n0; BAR
//   ph2:                             stage A_m1(t+1); BAR; MFMA m0n1; BAR
//   ph3: ds_read A_m1(8);            stage B_n1(t+1); BAR; MFMA m1n0; BAR
//   ph4:                             stage A_m0(t+2); BAR; MFMA m1n1;
//        VM2; BAR   <- VM BEFORE barrier so other waves' staged data landed
// vmcnt(2) leaves only the ph4-staged half in flight; everything tile t+1
// needs is guaranteed landed. Raw s_barrier (NOT __syncthreads) so the
// compiler does not drain vmcnt at barriers. Half-tiles are interleaved by
// per-wave m/n-half: A half h = rows with ((r>>6)&1)==h; B half h = rows
// with ((r>>5)&1)==h -> each staged half is exactly what one phase-pair
// consumes, and re-staging a region happens >=1 phase after its last read.
// ---------------------------------------------------------------------------
__global__ __launch_bounds__(512) void gemm256(const __bf16* __restrict__ A,
                                               const __bf16* __restrict__ BT,
                                               __bf16* __restrict__ Cc,
                                               int M, int N, int K) {
    __shared__ __attribute__((aligned(16))) char lds[131072];
    const int tid = threadIdx.x, lane = tid & 63, w = tid >> 6;
    const int wr = w >> 2, wc = w & 3, cc = lane & 15, gg = lane >> 4;

    // XCD-aware swizzle (gridDim.x % 8 == 0 for both call sites)
    const int cpx = gridDim.x >> 3;
    const int swz = ((int)blockIdx.x & 7) * cpx + ((int)blockIdx.x >> 3);
    const int nbx = N >> 8;
    const int rowBase = (swz / nbx) << 8;
    const int colBase = (swz % nbx) << 8;
    const int NT = K >> 6;

    const int sChunk = (lane & 7) ^ (lane >> 3);   // pre-swizzled src 16B chunk
    const int rsub   = lane >> 3;                  // row within 8-row group

    auto stA = [&](int t, int h) {
        const int buf = t & 1, k0 = (t % NT) * 64;
        #pragma unroll
        for (int l = 0; l < 2; ++l) {
            int idx   = l * 8 + w;
            int rbase = ((idx >> 3) << 7) + h * 64 + ((idx & 7) << 3);
            gload_lds16(A + (size_t)(rowBase + rbase + rsub) * K + k0 + sChunk * 8,
                        (__bf16*)(lds + buf * 65536 + rbase * 128 + lane * 16));
        }
    };
    auto stB = [&](int t, int h) {
        const int buf = t & 1, k0 = (t % NT) * 64;
        #pragma unroll
        for (int l = 0; l < 2; ++l) {
            int idx   = l * 8 + w;
            int rbase = ((idx >> 2) << 6) + h * 32 + ((idx & 3) << 3);
            gload_lds16(BT + (size_t)(colBase + rbase + rsub) * K + k0 + sChunk * 8,
                        (__bf16*)(lds + buf * 65536 + 32768 + rbase * 128 + lane * 16));
        }
    };

    f32x4 acc[8][4];
    #pragma unroll
    for (int i = 0; i < 8; ++i)
        #pragma unroll
        for (int j = 0; j < 4; ++j) acc[i][j] = f32x4{0.f, 0.f, 0.f, 0.f};
    bf16x8 afr[8], bfr[8];

    auto rdA = [&](int buf, int mh) {
        const char* base = lds + buf * 65536;
        #pragma unroll
        for (int i = 0; i < 4; ++i)
            #pragma unroll
            for (int kk = 0; kk < 2; ++kk) {
                int r  = wr * 128 + mh * 64 + i * 16 + cc;
                int cb = (kk * 64 + gg * 16) ^ ((cc & 7) << 4);
                afr[i * 2 + kk] = *(const bf16x8*)(base + r * 128 + cb);
            }
    };
    auto rdB = [&](int buf) {
        const char* base = lds + buf * 65536 + 32768;
        #pragma unroll
        for (int j = 0; j < 4; ++j)
            #pragma unroll
            for (int kk = 0; kk < 2; ++kk) {
                int r  = wc * 64 + j * 16 + cc;
                int cb = (kk * 64 + gg * 16) ^ ((cc & 7) << 4);
                bfr[j * 2 + kk] = *(const bf16x8*)(base + r * 128 + cb);
            }
    };

#define QMFMA(MH, NH)                                                        \
    _Pragma("unroll") for (int i = 0; i < 4; ++i)                            \
    _Pragma("unroll") for (int j = 0; j < 2; ++j)                            \
    _Pragma("unroll") for (int kk = 0; kk < 2; ++kk)                         \
        acc[(MH)*4 + i][(NH)*2 + j] = __builtin_amdgcn_mfma_f32_16x16x32_bf16( \
            afr[i*2 + kk], bfr[((NH)*2 + j)*2 + kk], acc[(MH)*4 + i][(NH)*2 + j], 0, 0, 0);

    // prologue: tile0 fully + tile1 A_m0; wait all but last half; sync
    stA(0, 0); stB(0, 0); stA(0, 1); stB(0, 1); stA(1, 0);
    VM2(); BAR();

    for (int t = 0; t < NT; ++t) {
        const int buf = t & 1;
        // ph1
        rdA(buf, 0); rdB(buf);
        stB(t + 1, 0);
        BAR();
        __builtin_amdgcn_s_setprio(1); QMFMA(0, 0); __builtin_amdgcn_s_setprio(0);
        BAR();
        // ph2
        stA(t + 1, 1);
        BAR();
        __builtin_amdgcn_s_setprio(1); QMFMA(0, 1); __builtin_amdgcn_s_setprio(0);
        BAR();
        // ph3
        rdA(buf, 1);
        stB(t + 1, 1);
        BAR();
        __builtin_amdgcn_s_setprio(1); QMFMA(1, 0); __builtin_amdgcn_s_setprio(0);
        BAR();
        // ph4
        stA(t + 2, 0);
        BAR();
        __builtin_amdgcn_s_setprio(1); QMFMA(1, 1); __builtin_amdgcn_s_setprio(0);
        VM2(); BAR();
    }
#undef QMFMA

    #pragma unroll
    for (int i = 0; i < 8; ++i)
        #pragma unroll
        for (int j = 0; j < 4; ++j) {
            const int col = colBase + wc * 64 + j * 16 + cc;
            #pragma unroll
            for (int rr = 0; rr < 4; ++rr) {
                const int row = rowBase + wr * 128 + (i >> 2) * 64 + (i & 3) * 16 + gg * 4 + rr;
                Cc[(size_t)row * N + col] = (__bf16)acc[i][j][rr];
            }
        }
}

// ---------------------------------------------------------------------------
// m97-structure bf16 GEMM: C[M,N] = A[M,K] @ BT[N,K]^T (+bias). (out-proj)
// ---------------------------------------------------------------------------
template <typename OutT, bool BIAS>
__global__ __launch_bounds__(256) void gemm_bt(const __bf16* __restrict__ A,
                                               const __bf16* __restrict__ BT,
                                               OutT* __restrict__ Cc,
                                               const float* __restrict__ bias,
                                               int M, int N, int K) {
    __shared__ __bf16 As[128 * 32];
    __shared__ __bf16 Bs[128 * 32];

    const int tid  = threadIdx.x;
    const int lane = tid & 63;
    const int w    = tid >> 6;
    const int wr   = w >> 1, wc = w & 1;
    const int cc   = lane & 15, gg = lane >> 4;
    const int rowBase = blockIdx.y * 128;
    const int colBase = blockIdx.x * 128;

    f32x4 acc[4][4];
    #pragma unroll
    for (int i = 0; i < 4; ++i)
        #pragma unroll
        for (int j = 0; j < 4; ++j) acc[i][j] = f32x4{0.f, 0.f, 0.f, 0.f};

    for (int k0 = 0; k0 < K; k0 += 32) {
        __syncthreads();
        #pragma unroll
        for (int i = 0; i < 2; ++i) {
            int idx = tid + 256 * i;
            int r   = idx >> 2;
            int c4  = idx & 3;
            gload_lds16(A  + (size_t)(rowBase + r) * K + k0 + c4 * 8, &As[idx * 8]);
            gload_lds16(BT + (size_t)(colBase + r) * K + k0 + c4 * 8, &Bs[idx * 8]);
        }
        __syncthreads();

        bf16x8 af[4], bfr2[4];
        #pragma unroll
        for (int i = 0; i < 4; ++i)
            af[i] = *(const bf16x8*)&As[(wr * 64 + i * 16 + cc) * 32 + gg * 8];
        #pragma unroll
        for (int j = 0; j < 4; ++j)
            bfr2[j] = *(const bf16x8*)&Bs[(wc * 64 + j * 16 + cc) * 32 + gg * 8];
        #pragma unroll
        for (int i = 0; i < 4; ++i)
            #pragma unroll
            for (int j = 0; j < 4; ++j)
                acc[i][j] = __builtin_amdgcn_mfma_f32_16x16x32_bf16(af[i], bfr2[j], acc[i][j], 0, 0, 0);
    }

    #pragma unroll
    for (int i = 0; i < 4; ++i)
        #pragma unroll
        for (int j = 0; j < 4; ++j) {
            const int col = colBase + wc * 64 + j * 16 + cc;
            #pragma unroll
            for (int r = 0; r < 4; ++r) {
                const int row = rowBase + wr * 64 + i * 16 + gg * 4 + r;
                float v = acc[i][j][r];
                if (BIAS) v += bias[col];
                Cc[(size_t)row * N + col] = (OutT)v;
            }
        }
}

// ---------------------------------------------------------------------------
// MFMA flash attention v7 = r0 structure (pair-fused causal blocks, grid
// (64,8), uniform 34 tile-computes per wave) + T12 in-register P (no Ps LDS).
// S^T = mfma(K_frag, Q_frag): col = q = lane&31,
//       row = key = (r&3) + 8*(r>>2) + 4*(lane>>5)   [guide m74/m101]
// Fixed-max softmax p = exp2(s*0.125*log2e - 16*log2e); L per-lane + one
// shfl_xor(32) at the end.
// ---------------------------------------------------------------------------
__global__ __launch_bounds__(256) void flash_attn_mfma(const __bf16* __restrict__ qkv,
                                                       const __bf16* __restrict__ Vt,
                                                       __bf16* __restrict__ ctx) {
    constexpr int T = 2048, C = 1024, HD = 64;
    constexpr int R3C = 3 * C;
    constexpr float K1 = 0.125f * 1.44269504088896f;   // scale * log2e
    constexpr float K2 = -16.0f * 1.44269504088896f;   // -M0 * log2e

    const int tid  = threadIdx.x;
    const int lane = tid & 63;
    const int w    = tid >> 6;
    const int q5   = lane & 31;
    const int half = lane >> 5;

    const int bh   = blockIdx.x;               // 0..63
    const int y    = blockIdx.y;               // 0..7
    const int qtA  = 15 - y;                   // heavy tile
    const int qtB  = y;                        // light tile (rides free)
    const int b    = bh >> 4;
    const int h    = bh & 15;
    const int srowA = qtA * 128 + w * 32;
    const int srowB = qtB * 128 + w * 32;
    const int ktmaxA = qtA * 128 + 64;
    const int ktmaxB = qtB * 128 + 64;

    __shared__ __attribute__((aligned(16))) __bf16 Ks [64][72];   // [key][hd]
    __shared__ __attribute__((aligned(16))) __bf16 VsT[64][72];   // [hd][key]

    const __bf16* QrowA = qkv + (size_t)(b * T + srowA + q5) * R3C + h * HD;
    const __bf16* QrowB = qkv + (size_t)(b * T + srowB + q5) * R3C + h * HD;
    bf16x8 QbA[4], QbB[4];
    #pragma unroll
    for (int ks = 0; ks < 4; ++ks) {
        QbA[ks] = *(const bf16x8*)(QrowA + ks * 16 + half * 8);
        QbB[ks] = *(const bf16x8*)(QrowB + ks * 16 + half * 8);
    }

    f32x16 OA[2], OB[2];
    #pragma unroll
    for (int mb = 0; mb < 2; ++mb)
        #pragma unroll
        for (int r = 0; r < 16; ++r) { OA[mb][r] = 0.f; OB[mb][r] = 0.f; }
    float lsumA = 0.f, lsumB = 0.f;

    const __bf16* Kb  = qkv + (size_t)(b * T) * R3C + C + h * HD;
    const __bf16* Vtb = Vt + (size_t)bh * 64 * T;

    for (int kt = 0; kt <= ktmaxA; kt += 64) {
        __syncthreads();
        #pragma unroll
        for (int i = 0; i < 2; ++i) {
            int idx = tid + 256 * i;
            int kr  = idx >> 3;
            int c8  = idx & 7;
            *(uint4*)&Ks[kr][c8 * 8] = *(const uint4*)(Kb + (size_t)(kt + kr) * R3C + c8 * 8);
        }
        #pragma unroll
        for (int i = 0; i < 2; ++i) {
            int idx = tid + 256 * i;
            int d   = idx >> 3;
            int k8  = idx & 7;
            *(uint4*)&VsT[d][k8 * 8] = *(const uint4*)(Vtb + (size_t)d * T + kt + k8 * 8);
        }
        __syncthreads();

        // one 32-key sub-tile: S -> mask -> exp -> T12 pack -> PV
        auto subtile = [&](int sub, const bf16x8* Qb, int srow, f32x16* O, float& lsum) {
            f32x16 S;
            #pragma unroll
            for (int r = 0; r < 16; ++r) S[r] = 0.f;
            #pragma unroll
            for (int ks = 0; ks < 4; ++ks) {
                bf16x8 kb = *(const bf16x8*)&Ks[sub * 32 + q5][ks * 16 + half * 8];
                S = __builtin_amdgcn_mfma_f32_32x32x16_bf16(kb, Qb[ks], S, 0, 0, 0);
            }
            if (kt + sub * 32 + 31 > srow) {
                #pragma unroll
                for (int r = 0; r < 16; ++r) {
                    int key = kt + sub * 32 + (r & 3) + 8 * (r >> 2) + 4 * half;
                    if (key > srow + q5) S[r] = -1e30f;
                }
            }
            float p[16];
            #pragma unroll
            for (int r = 0; r < 16; ++r) {
                p[r] = exp2f(fmaf(S[r], K1, K2));
                lsum += p[r];
            }
            unsigned w0 = packbf(p[0],  p[1]);
            unsigned w1 = packbf(p[2],  p[3]);
            unsigned w2 = packbf(p[4],  p[5]);
            unsigned w3 = packbf(p[6],  p[7]);
            permswap(w0, w2);
            permswap(w1, w3);
            unsigned w4 = packbf(p[8],  p[9]);
            unsigned w5 = packbf(p[10], p[11]);
            unsigned w6 = packbf(p[12], p[13]);
            unsigned w7 = packbf(p[14], p[15]);
            permswap(w4, w6);
            permswap(w5, w7);
            union { unsigned u[4]; bf16x8 v; } pf0, pf1;
            pf0.u[0] = w0; pf0.u[1] = w1; pf0.u[2] = w2; pf0.u[3] = w3;
            pf1.u[0] = w4; pf1.u[1] = w5; pf1.u[2] = w6; pf1.u[3] = w7;
            const int vc = sub * 32 + half * 8;
            #pragma unroll
            for (int mb = 0; mb < 2; ++mb) {
                bf16x8 v0 = *(const bf16x8*)&VsT[mb * 32 + q5][vc];
                O[mb] = __builtin_amdgcn_mfma_f32_32x32x16_bf16(v0, pf0.v, O[mb], 0, 0, 0);
                bf16x8 v1 = *(const bf16x8*)&VsT[mb * 32 + q5][vc + 16];
                O[mb] = __builtin_amdgcn_mfma_f32_32x32x16_bf16(v1, pf1.v, O[mb], 0, 0, 0);
            }
        };

        #pragma unroll
        for (int sub = 0; sub < 2; ++sub)
            subtile(sub, QbA, srowA, OA, lsumA);
        if (kt <= ktmaxB) {
            #pragma unroll
            for (int sub = 0; sub < 2; ++sub)
                subtile(sub, QbB, srowB, OB, lsumB);
        }
    }

    const float invA = 1.f / (lsumA + __shfl_xor(lsumA, 32));
    const float invB = 1.f / (lsumB + __shfl_xor(lsumB, 32));

    __bf16* crowA = ctx + (size_t)(b * T + srowA + q5) * C + h * HD;
    __bf16* crowB = ctx + (size_t)(b * T + srowB + q5) * C + h * HD;
    #pragma unroll
    for (int mb = 0; mb < 2; ++mb)
        #pragma unroll
        for (int a = 0; a < 4; ++a) {
            union { bf16x4 v; uint2 u; } pA, pB;
            #pragma unroll
            for (int bq = 0; bq < 4; ++bq) {
                pA.v[bq] = (__bf16)(OA[mb][4 * a + bq] * invA);
                pB.v[bq] = (__bf16)(OB[mb][4 * a + bq] * invB);
            }
            *(uint2*)(crowA + mb * 32 + 8 * a + 4 * half) = pA.u;
            *(uint2*)(crowB + mb * 32 + 8 * a + 4 * half) = pB.u;
        }
}

extern "C" void kernel_launch(void* const* d_in, const int* in_sizes, int n_in,
                              void* d_out, int out_size, void* d_ws, size_t ws_size,
                              hipStream_t stream) {
    constexpr int B = 4, T = 2048, C = 1024;
    constexpr int M = B * T;          // 8192

    const float* x     = (const float*)d_in[0];
    const float* w_qkv = (const float*)d_in[1];
    const float* w_out = (const float*)d_in[2];
    const float* b_out = (const float*)d_in[3];
    float* out = (float*)d_out;

    char* ws = (char*)d_ws;
    __bf16* xb     = (__bf16*)(ws);                      // 16 MB
    __bf16* wqkvT  = (__bf16*)(ws + (16ull << 20));      //  6 MB
    __bf16* woutT  = (__bf16*)(ws + (22ull << 20));      //  2 MB
    __bf16* qkvb   = (__bf16*)(ws + (24ull << 20));      // 48 MB
    __bf16* ctxb   = (__bf16*)(ws + (72ull << 20));      // 16 MB
    __bf16* Vt     = (__bf16*)(ws + (88ull << 20));      // 16 MB

    // 0) casts / transposes
    cast_bf16<<<(M * C / 4 + 255) / 256, 256, 0, stream>>>(x, xb, M * C / 4);
    transpose_cast<<<dim3(3 * C / 32, C / 32), 256, 0, stream>>>(w_qkv, wqkvT, C, 3 * C);
    transpose_cast<<<dim3(C / 32, C / 32), 256, 0, stream>>>(w_out, woutT, C, C);

    // 1) qkv = xb @ wqkvT^T  (bf16 out) -- 256^2 pipelined GEMM
    //    grid = (8192/256) * (3072/256) = 32*12 = 384 blocks (384 % 8 == 0)
    gemm256<<<384, 512, 0, stream>>>(xb, wqkvT, qkvb, M, 3 * C, C);

    // 1b) V transpose
    transpose_v<<<dim3(T / 64, B * 16), 256, 0, stream>>>(qkvb, Vt);

    // 2) MFMA flash attention -> ctxb (pair-fused grid + in-register P)
    flash_attn_mfma<<<dim3(B * 16, 8), 256, 0, stream>>>(qkvb, Vt, ctxb);

    // 3) out = ctxb @ woutT^T + b_out (fp32 out)
    gemm_bt<float, true><<<dim3(C / 128, M / 128), 256, 0, stream>>>(
        ctxb, woutT, out, b_out, M, C, C);
}